// Round 9
// baseline (49.339 us; speedup 1.0000x reference)
//
#include <hip/hip_runtime.h>
#include <math.h>

#define D 512
#define NREL 512
#define NB 1024
#define FLAG_SET 0x13572468u
#define FLAG_STRIDE 32           // uints -> 128 B per flag line

typedef _Float16 f16x8 __attribute__((ext_vector_type(8)));
typedef float f32x4 __attribute__((ext_vector_type(4)));

__device__ __forceinline__ float wave_sum(float v) {
#pragma unroll
    for (int m = 1; m < 64; m <<= 1) v += __shfl_xor(v, m, 64);
    return v;
}

// ---- one wave: query row b -> A3 (fp16), x2[b] ------------------------------
__device__ __forceinline__ void prep_q_row(
        int b, int lane,
        const float* __restrict__ ent, const int* __restrict__ trip,
        const float* __restrict__ grot,
        _Float16* __restrict__ A3, float* __restrict__ x2) {
    const float c = 0.01f, sc = 0.1f;
    const int si = trip[3 * b], oi = trip[3 * b + 2];
    const float* ps = ent + (size_t)si * D + lane * 8;
    const float* po = ent + (size_t)oi * D + lane * 8;
    const float4 s0 = *(const float4*)ps, s1 = *(const float4*)(ps + 4);
    const float4 o0 = *(const float4*)po, o1 = *(const float4*)(po + 4);
    const float ss = wave_sum(s0.x*s0.x + s0.y*s0.y + s0.z*s0.z + s0.w*s0.w
                            + s1.x*s1.x + s1.y*s1.y + s1.z*s1.z + s1.w*s1.w);
    const float oo = wave_sum(o0.x*o0.x + o0.y*o0.y + o0.z*o0.z + o0.w*o0.w
                            + o1.x*o1.x + o1.y*o1.y + o1.z*o1.z + o1.w*o1.w);
    const float n_s = fmaxf(sqrtf(ss), 1e-15f);
    const float arg = fminf(fmaxf(sc * n_s, -1.0f + 1e-7f), 1.0f - 1e-7f);
    const float ls  = atanhf(arg) / (sc * n_s);
    const float4 ang = *(const float4*)(grot + 4 * lane);
    float sa0, ca0, sa1, ca1, sa2, ca2, sa3, ca3;
    sincosf(ang.x, &sa0, &ca0); sincosf(ang.y, &sa1, &ca1);
    sincosf(ang.z, &sa2, &ca2); sincosf(ang.w, &sa3, &ca3);
    const float x0 = ls*s0.x, x1 = ls*s0.y, x2v = ls*s0.z, x3 = ls*s0.w;
    const float x4 = ls*s1.x, x5 = ls*s1.y, x6 = ls*s1.z, x7 = ls*s1.w;
    const float ux0 = ca0*x0 - sa0*x1, uy0 = sa0*x0 + ca0*x1;
    const float ux1 = ca1*x2v - sa1*x3, uy1 = sa1*x2v + ca1*x3;
    const float ux2 = ca2*x4 - sa2*x5, uy2 = sa2*x4 + ca2*x5;
    const float ux3 = ca3*x6 - sa3*x7, uy3 = sa3*x6 + ca3*x7;
    const float uo = wave_sum(ux0*o0.x + uy0*o0.y + ux1*o0.z + uy1*o0.w
                            + ux2*o1.x + uy2*o1.y + ux3*o1.z + uy3*o1.w);
    // ||u|| = ls*||s|| (rotation orthogonal); ||es*u|| = es*||u||
    const float n_u = ls * n_s;
    const float tt  = tanhf(sc * n_u);
    const float es  = tt / (sc * n_u);
    const float rn  = tt / sc;               // es * n_u
    const float rr  = rn * rn;
    const float ro  = es * uo;
    const float A1  = 1.0f - 2.0f*c*ro + c*oo;
    const float B1  = 1.0f - c*rr;
    const float den = fmaxf(1.0f - 2.0f*c*ro + c*c*rr*oo, 1e-15f);
    const float inv = 1.0f / den;
    const float qa  = -A1 * es * inv, qb = B1 * inv;
    f16x8 h;
    h[0] = (_Float16)(qa*ux0 + qb*o0.x); h[1] = (_Float16)(qa*uy0 + qb*o0.y);
    h[2] = (_Float16)(qa*ux1 + qb*o0.z); h[3] = (_Float16)(qa*uy1 + qb*o0.w);
    h[4] = (_Float16)(qa*ux2 + qb*o1.x); h[5] = (_Float16)(qa*uy2 + qb*o1.y);
    h[6] = (_Float16)(qa*ux3 + qb*o1.z); h[7] = (_Float16)(qa*uy3 + qb*o1.w);
    *(f16x8*)(A3 + (size_t)b * D + lane * 8) = h;
    if (lane == 0)
        x2[b] = (A1*A1*rr - 2.0f*A1*B1*ro + B1*B1*oo) * inv * inv;
}

// ---- one wave: rel_hyp row r -> B3 (fp16), y2[r] ----------------------------
__device__ __forceinline__ void prep_rel_row(
        int r, int lane, const float* __restrict__ rel,
        _Float16* __restrict__ B3, float* __restrict__ y2) {
    const float sc = 0.1f;
    const float* src = rel + (size_t)r * D + lane * 8;
    const float4 u0 = *(const float4*)src;
    const float4 u1 = *(const float4*)(src + 4);
    const float uu = wave_sum(u0.x*u0.x + u0.y*u0.y + u0.z*u0.z + u0.w*u0.w
                            + u1.x*u1.x + u1.y*u1.y + u1.z*u1.z + u1.w*u1.w);
    const float n  = fmaxf(sqrtf(uu), 1e-15f);
    const float es = tanhf(sc * n) / (sc * n);
    f16x8 h;
    h[0] = (_Float16)(es*u0.x); h[1] = (_Float16)(es*u0.y);
    h[2] = (_Float16)(es*u0.z); h[3] = (_Float16)(es*u0.w);
    h[4] = (_Float16)(es*u1.x); h[5] = (_Float16)(es*u1.y);
    h[6] = (_Float16)(es*u1.z); h[7] = (_Float16)(es*u1.w);
    *(f16x8*)(B3 + (size_t)r * D + lane * 8) = h;
    if (lane == 0) y2[r] = es * es * uu;
}

// ---- single fused kernel: 256 blocks (1/CU), flag-based producer-consumer --
__global__ __launch_bounds__(256) void fused_kernel(
        const float* __restrict__ ent, const float* __restrict__ rel,
        const int* __restrict__ trip, const float* __restrict__ grot,
        const float* __restrict__ bias, float* __restrict__ out,
        _Float16* __restrict__ A3, _Float16* __restrict__ B3,
        float* __restrict__ x2, float* __restrict__ y2,
        unsigned int* __restrict__ flags) {
    const int t = threadIdx.x, wid = t >> 6, lane = t & 63;
    const int b = blockIdx.x;                    // 0..255

    // --- prep: this block produces q-rows 4b..4b+3 and rel-rows 2b, 2b+1 ----
    prep_q_row(4 * b + wid, lane, ent, trip, grot, A3, x2);
    if (wid >= 2) prep_rel_row(2 * b + (wid - 2), lane, rel, B3, y2);

    __threadfence();
    __syncthreads();
    if (t == 0)
        __hip_atomic_store(&flags[(size_t)b * FLAG_STRIDE], FLAG_SET,
                           __ATOMIC_RELEASE, __HIP_MEMORY_SCOPE_AGENT);

    // --- wait for the 32 producer blocks of this tile ------------------------
    const int mt = b >> 4, nt = b & 15;          // m-tile (64 rows), n-tile (32)
    int fidx;
    if (lane < 16)      fidx = 16 * mt + lane;          // q-row producers
    else if (lane < 32) fidx = 16 * nt + (lane - 16);   // rel-row producers
    else                fidx = b;                        // own flag (already set)
    for (;;) {
        const unsigned int v = __hip_atomic_load(
            &flags[(size_t)fidx * FLAG_STRIDE],
            __ATOMIC_ACQUIRE, __HIP_MEMORY_SCOPE_AGENT);
        if (__all(v == FLAG_SET)) break;
        __builtin_amdgcn_s_sleep(1);
    }

    // --- score: 64x32 tile; 4 waves = 2 m-halves (wm) x 2 K-halves (kh) -----
    const int wm = wid & 1, kh = wid >> 1;
    const int m0 = mt * 64 + wm * 32;
    const int n0 = nt * 32;
    const int row = lane & 15, kg = lane >> 4;

    const f16x8* pa0 = (const f16x8*)(A3 + (size_t)(m0 + row) * D) + kg;
    const f16x8* pa1 = (const f16x8*)(A3 + (size_t)(m0 + 16 + row) * D) + kg;
    const f16x8* pb0 = (const f16x8*)(B3 + (size_t)(n0 + row) * D) + kg;
    const f16x8* pb1 = (const f16x8*)(B3 + (size_t)(n0 + 16 + row) * D) + kg;

    f32x4 acc[2][2] = {};
    const int k8beg = kh * 32, k8end = k8beg + 32;
#pragma unroll 4
    for (int k8 = k8beg; k8 < k8end; k8 += 4) {
        const f16x8 a0 = pa0[k8], a1 = pa1[k8];
        const f16x8 b0 = pb0[k8], b1 = pb1[k8];
        acc[0][0] = __builtin_amdgcn_mfma_f32_16x16x32_f16(a0, b0, acc[0][0], 0, 0, 0);
        acc[0][1] = __builtin_amdgcn_mfma_f32_16x16x32_f16(a0, b1, acc[0][1], 0, 0, 0);
        acc[1][0] = __builtin_amdgcn_mfma_f32_16x16x32_f16(a1, b0, acc[1][0], 0, 0, 0);
        acc[1][1] = __builtin_amdgcn_mfma_f32_16x16x32_f16(a1, b1, acc[1][1], 0, 0, 0);
    }

    __shared__ f32x4 lacc[2][64][4];
    if (kh == 1) {
#pragma unroll
        for (int i = 0; i < 2; ++i)
#pragma unroll
            for (int j = 0; j < 2; ++j) lacc[wm][lane][i * 2 + j] = acc[i][j];
    }
    __syncthreads();
    if (kh == 0) {
#pragma unroll
        for (int i = 0; i < 2; ++i)
#pragma unroll
            for (int j = 0; j < 2; ++j) acc[i][j] += lacc[wm][lane][i * 2 + j];

        // C/D layout: col = lane&15, row = (lane>>4)*4 + reg
        const float c = 0.01f;
        const int crow = (lane >> 4) * 4;
        const int ccol = lane & 15;
#pragma unroll
        for (int i = 0; i < 2; ++i) {
#pragma unroll
            for (int r = 0; r < 4; ++r) {
                const int m = m0 + i * 16 + crow + r;
                const float X2 = x2[m];
                const float B1 = 1.0f - c * X2;
#pragma unroll
                for (int j = 0; j < 2; ++j) {
                    const int n  = n0 + j * 16 + ccol;
                    const float qd = acc[i][j][r];
                    const float Y2 = y2[n];
                    const float A1  = 1.0f - 2.0f * c * qd + c * Y2;
                    const float den = fmaxf(1.0f - 2.0f * c * qd + c * c * X2 * Y2, 1e-15f);
                    const float num2 = A1 * A1 * X2 - 2.0f * A1 * B1 * qd + B1 * B1 * Y2;
                    out[(size_t)m * NREL + n] = -(num2 / (den * den)) + bias[n];
                }
            }
        }
    }
}

extern "C" void kernel_launch(void* const* d_in, const int* in_sizes, int n_in,
                              void* d_out, int out_size, void* d_ws, size_t ws_size,
                              hipStream_t stream) {
    const float* ent  = (const float*)d_in[0];   // (20000, 512)
    const float* rel  = (const float*)d_in[1];   // (512, 512)
    const int*   trip = (const int*)d_in[2];     // (1024, 3)
    const float* grot = (const float*)d_in[3];   // (256,)
    const float* bias = (const float*)d_in[4];   // (512,)
    float* out = (float*)d_out;                  // (1024, 512)

    _Float16* A3 = (_Float16*)d_ws;              // 1024*512 fp16
    _Float16* B3 = A3 + (size_t)NB * D;          // 512*512 fp16
    float* x2 = (float*)(B3 + (size_t)NREL * D); // 1024 f32
    float* y2 = x2 + NB;                         // 512 f32
    unsigned int* flags = (unsigned int*)(y2 + NREL);  // 256 x 128B lines

    fused_kernel<<<dim3(256), dim3(256), 0, stream>>>(
        ent, rel, trip, grot, bias, out, A3, B3, x2, y2, flags);
}

// Round 10
// 16.781 us; speedup vs baseline: 2.9402x; 2.9402x over previous
//
#include <hip/hip_runtime.h>
#include <math.h>

#define D 512
#define NREL 512
#define NB 1024

typedef _Float16 f16x8 __attribute__((ext_vector_type(8)));
typedef float f32x4 __attribute__((ext_vector_type(4)));

__device__ __forceinline__ float wave_sum(float v) {
#pragma unroll
    for (int m = 1; m < 64; m <<= 1) v += __shfl_xor(v, m, 64);
    return v;
}

// ---- one wave: rel_hyp row r -> B3 (fp16), y2[r] ----------------------------
__device__ __forceinline__ void prep_rel_row(
        int r, int lane, const float* __restrict__ rel,
        _Float16* __restrict__ B3, float* __restrict__ y2) {
    const float sc = 0.1f;
    const float* src = rel + (size_t)r * D + lane * 8;
    const float4 u0 = *(const float4*)src;
    const float4 u1 = *(const float4*)(src + 4);
    const float uu = wave_sum(u0.x*u0.x + u0.y*u0.y + u0.z*u0.z + u0.w*u0.w
                            + u1.x*u1.x + u1.y*u1.y + u1.z*u1.z + u1.w*u1.w);
    const float n  = fmaxf(sqrtf(uu), 1e-15f);
    const float es = tanhf(sc * n) / (sc * n);
    f16x8 h;
    h[0] = (_Float16)(es*u0.x); h[1] = (_Float16)(es*u0.y);
    h[2] = (_Float16)(es*u0.z); h[3] = (_Float16)(es*u0.w);
    h[4] = (_Float16)(es*u1.x); h[5] = (_Float16)(es*u1.y);
    h[6] = (_Float16)(es*u1.z); h[7] = (_Float16)(es*u1.w);
    *(f16x8*)(B3 + (size_t)r * D + lane * 8) = h;
    if (lane == 0) y2[r] = es * es * uu;
}

// ---- one wave: query row b -> A3 (fp16), x2[b] ------------------------------
__device__ __forceinline__ void prep_q_row(
        int b, int lane,
        const float* __restrict__ ent, const int* __restrict__ trip,
        const float* __restrict__ grot,
        _Float16* __restrict__ A3, float* __restrict__ x2) {
    const float c = 0.01f, sc = 0.1f;
    const int si = trip[3 * b], oi = trip[3 * b + 2];
    const float* ps = ent + (size_t)si * D + lane * 8;
    const float* po = ent + (size_t)oi * D + lane * 8;
    const float4 s0 = *(const float4*)ps, s1 = *(const float4*)(ps + 4);
    const float4 o0 = *(const float4*)po, o1 = *(const float4*)(po + 4);
    const float ss = wave_sum(s0.x*s0.x + s0.y*s0.y + s0.z*s0.z + s0.w*s0.w
                            + s1.x*s1.x + s1.y*s1.y + s1.z*s1.z + s1.w*s1.w);
    const float oo = wave_sum(o0.x*o0.x + o0.y*o0.y + o0.z*o0.z + o0.w*o0.w
                            + o1.x*o1.x + o1.y*o1.y + o1.z*o1.z + o1.w*o1.w);
    const float n_s = fmaxf(sqrtf(ss), 1e-15f);
    const float arg = fminf(fmaxf(sc * n_s, -1.0f + 1e-7f), 1.0f - 1e-7f);
    const float ls  = atanhf(arg) / (sc * n_s);
    const float4 ang = *(const float4*)(grot + 4 * lane);
    float sa0, ca0, sa1, ca1, sa2, ca2, sa3, ca3;
    sincosf(ang.x, &sa0, &ca0); sincosf(ang.y, &sa1, &ca1);
    sincosf(ang.z, &sa2, &ca2); sincosf(ang.w, &sa3, &ca3);
    const float x0 = ls*s0.x, x1 = ls*s0.y, x2v = ls*s0.z, x3 = ls*s0.w;
    const float x4 = ls*s1.x, x5 = ls*s1.y, x6 = ls*s1.z, x7 = ls*s1.w;
    const float ux0 = ca0*x0 - sa0*x1, uy0 = sa0*x0 + ca0*x1;
    const float ux1 = ca1*x2v - sa1*x3, uy1 = sa1*x2v + ca1*x3;
    const float ux2 = ca2*x4 - sa2*x5, uy2 = sa2*x4 + ca2*x5;
    const float ux3 = ca3*x6 - sa3*x7, uy3 = sa3*x6 + ca3*x7;
    const float uo = wave_sum(ux0*o0.x + uy0*o0.y + ux1*o0.z + uy1*o0.w
                            + ux2*o1.x + uy2*o1.y + ux3*o1.z + uy3*o1.w);
    // ||u|| = ls*||s|| (rotation orthogonal); ||es*u|| = es*||u||
    const float n_u = ls * n_s;
    const float tt  = tanhf(sc * n_u);
    const float es  = tt / (sc * n_u);
    const float rn  = tt / sc;               // es * n_u
    const float rr  = rn * rn;
    const float ro  = es * uo;
    const float A1  = 1.0f - 2.0f*c*ro + c*oo;
    const float B1  = 1.0f - c*rr;
    const float den = fmaxf(1.0f - 2.0f*c*ro + c*c*rr*oo, 1e-15f);
    const float inv = 1.0f / den;
    const float qa  = -A1 * es * inv, qb = B1 * inv;
    f16x8 h;
    h[0] = (_Float16)(qa*ux0 + qb*o0.x); h[1] = (_Float16)(qa*uy0 + qb*o0.y);
    h[2] = (_Float16)(qa*ux1 + qb*o0.z); h[3] = (_Float16)(qa*uy1 + qb*o0.w);
    h[4] = (_Float16)(qa*ux2 + qb*o1.x); h[5] = (_Float16)(qa*uy2 + qb*o1.y);
    h[6] = (_Float16)(qa*ux3 + qb*o1.z); h[7] = (_Float16)(qa*uy3 + qb*o1.w);
    *(f16x8*)(A3 + (size_t)b * D + lane * 8) = h;
    if (lane == 0)
        x2[b] = (A1*A1*rr - 2.0f*A1*B1*ro + B1*B1*oo) * inv * inv;
}

// ---- prep: 1536 waves; rel/q interleaved within blocks for tail balance ----
// gid%3==0 -> rel row gid/3 (512 rows); else -> q row gid - gid/3 - 1 (1024)
__global__ __launch_bounds__(256) void prep_kernel(
        const float* __restrict__ ent, const float* __restrict__ rel,
        const int* __restrict__ trip, const float* __restrict__ grot,
        _Float16* __restrict__ A3, _Float16* __restrict__ B3,
        float* __restrict__ x2, float* __restrict__ y2) {
    const int t = threadIdx.x, wid = t >> 6, lane = t & 63;
    const int gid = blockIdx.x * 4 + wid;        // 0..1535
    const int g3 = gid / 3;
    if (gid % 3 == 0) prep_rel_row(g3, lane, rel, B3, y2);
    else              prep_q_row(gid - g3 - 1, lane, ent, trip, grot, A3, x2);
}

// ---- score: 64x32 tile / 256-thr block (R6-proven) -------------------------
// 4 waves = 2 m-halves (wm) x 2 K-halves (kh), LDS combine
__global__ __launch_bounds__(256) void score_mfma(
        const _Float16* __restrict__ A3, const _Float16* __restrict__ B3,
        const float* __restrict__ x2, const float* __restrict__ y2,
        const float* __restrict__ bias, float* __restrict__ out) {
    const int t = threadIdx.x, wid = t >> 6, lane = t & 63;
    const int wm = wid & 1, kh = wid >> 1;
    const int m0 = blockIdx.y * 64 + wm * 32;
    const int n0 = blockIdx.x * 32;
    const int row = lane & 15, kg = lane >> 4;

    const f16x8* pa0 = (const f16x8*)(A3 + (size_t)(m0 + row) * D) + kg;
    const f16x8* pa1 = (const f16x8*)(A3 + (size_t)(m0 + 16 + row) * D) + kg;
    const f16x8* pb0 = (const f16x8*)(B3 + (size_t)(n0 + row) * D) + kg;
    const f16x8* pb1 = (const f16x8*)(B3 + (size_t)(n0 + 16 + row) * D) + kg;

    f32x4 acc[2][2] = {};
    const int k8beg = kh * 32, k8end = k8beg + 32;
#pragma unroll 4
    for (int k8 = k8beg; k8 < k8end; k8 += 4) {
        const f16x8 a0 = pa0[k8], a1 = pa1[k8];
        const f16x8 b0 = pb0[k8], b1 = pb1[k8];
        acc[0][0] = __builtin_amdgcn_mfma_f32_16x16x32_f16(a0, b0, acc[0][0], 0, 0, 0);
        acc[0][1] = __builtin_amdgcn_mfma_f32_16x16x32_f16(a0, b1, acc[0][1], 0, 0, 0);
        acc[1][0] = __builtin_amdgcn_mfma_f32_16x16x32_f16(a1, b0, acc[1][0], 0, 0, 0);
        acc[1][1] = __builtin_amdgcn_mfma_f32_16x16x32_f16(a1, b1, acc[1][1], 0, 0, 0);
    }

    __shared__ f32x4 lacc[2][64][4];
    if (kh == 1) {
#pragma unroll
        for (int i = 0; i < 2; ++i)
#pragma unroll
            for (int j = 0; j < 2; ++j) lacc[wm][lane][i * 2 + j] = acc[i][j];
    }
    __syncthreads();
    if (kh == 0) {
#pragma unroll
        for (int i = 0; i < 2; ++i)
#pragma unroll
            for (int j = 0; j < 2; ++j) acc[i][j] += lacc[wm][lane][i * 2 + j];

        // C/D layout: col = lane&15, row = (lane>>4)*4 + reg
        const float c = 0.01f;
        const int crow = (lane >> 4) * 4;
        const int ccol = lane & 15;
#pragma unroll
        for (int i = 0; i < 2; ++i) {
#pragma unroll
            for (int r = 0; r < 4; ++r) {
                const int m = m0 + i * 16 + crow + r;
                const float X2 = x2[m];
                const float B1 = 1.0f - c * X2;
#pragma unroll
                for (int j = 0; j < 2; ++j) {
                    const int n  = n0 + j * 16 + ccol;
                    const float qd = acc[i][j][r];
                    const float Y2 = y2[n];
                    const float A1  = 1.0f - 2.0f * c * qd + c * Y2;
                    const float den = fmaxf(1.0f - 2.0f * c * qd + c * c * X2 * Y2, 1e-15f);
                    const float num2 = A1 * A1 * X2 - 2.0f * A1 * B1 * qd + B1 * B1 * Y2;
                    out[(size_t)m * NREL + n] = -(num2 / (den * den)) + bias[n];
                }
            }
        }
    }
}

extern "C" void kernel_launch(void* const* d_in, const int* in_sizes, int n_in,
                              void* d_out, int out_size, void* d_ws, size_t ws_size,
                              hipStream_t stream) {
    const float* ent  = (const float*)d_in[0];   // (20000, 512)
    const float* rel  = (const float*)d_in[1];   // (512, 512)
    const int*   trip = (const int*)d_in[2];     // (1024, 3)
    const float* grot = (const float*)d_in[3];   // (256,)
    const float* bias = (const float*)d_in[4];   // (512,)
    float* out = (float*)d_out;                  // (1024, 512)

    _Float16* A3 = (_Float16*)d_ws;              // 1024*512 fp16
    _Float16* B3 = A3 + (size_t)NB * D;          // 512*512 fp16
    float* x2 = (float*)(B3 + (size_t)NREL * D);
    float* y2 = x2 + NB;

    prep_kernel<<<dim3((NREL + NB) / 4), dim3(256), 0, stream>>>(
        ent, rel, trip, grot, A3, B3, x2, y2);
    score_mfma<<<dim3(NREL / 32, NB / 64), dim3(256), 0, stream>>>(
        A3, B3, x2, y2, bias, out);
}

// Round 11
// 16.542 us; speedup vs baseline: 2.9826x; 1.0144x over previous
//
#include <hip/hip_runtime.h>
#include <math.h>

#define D 512
#define NREL 512
#define NB 1024

typedef _Float16 f16x8 __attribute__((ext_vector_type(8)));
typedef float f32x4 __attribute__((ext_vector_type(4)));

__device__ __forceinline__ float wave_sum(float v) {
#pragma unroll
    for (int m = 1; m < 64; m <<= 1) v += __shfl_xor(v, m, 64);
    return v;
}

// ---- one wave: rel_hyp row r -> B3 (fp16), y2[r] ----------------------------
__device__ __forceinline__ void prep_rel_row(
        int r, int lane, const float* __restrict__ rel,
        _Float16* __restrict__ B3, float* __restrict__ y2) {
    const float sc = 0.1f;
    const float* src = rel + (size_t)r * D + lane * 8;
    const float4 u0 = *(const float4*)src;
    const float4 u1 = *(const float4*)(src + 4);
    const float uu = wave_sum(u0.x*u0.x + u0.y*u0.y + u0.z*u0.z + u0.w*u0.w
                            + u1.x*u1.x + u1.y*u1.y + u1.z*u1.z + u1.w*u1.w);
    const float n  = fmaxf(sqrtf(uu), 1e-15f);
    const float es = tanhf(sc * n) / (sc * n);
    f16x8 h;
    h[0] = (_Float16)(es*u0.x); h[1] = (_Float16)(es*u0.y);
    h[2] = (_Float16)(es*u0.z); h[3] = (_Float16)(es*u0.w);
    h[4] = (_Float16)(es*u1.x); h[5] = (_Float16)(es*u1.y);
    h[6] = (_Float16)(es*u1.z); h[7] = (_Float16)(es*u1.w);
    *(f16x8*)(B3 + (size_t)r * D + lane * 8) = h;
    if (lane == 0) y2[r] = es * es * uu;
}

// ---- one wave: query row b -> A3 (fp16), x2[b] ------------------------------
__device__ __forceinline__ void prep_q_row(
        int b, int lane,
        const float* __restrict__ ent, const int* __restrict__ trip,
        const float* __restrict__ grot,
        _Float16* __restrict__ A3, float* __restrict__ x2) {
    const float c = 0.01f, sc = 0.1f;
    const int si = trip[3 * b], oi = trip[3 * b + 2];
    const float* ps = ent + (size_t)si * D + lane * 8;
    const float* po = ent + (size_t)oi * D + lane * 8;
    const float4 s0 = *(const float4*)ps, s1 = *(const float4*)(ps + 4);
    const float4 o0 = *(const float4*)po, o1 = *(const float4*)(po + 4);
    const float ss = wave_sum(s0.x*s0.x + s0.y*s0.y + s0.z*s0.z + s0.w*s0.w
                            + s1.x*s1.x + s1.y*s1.y + s1.z*s1.z + s1.w*s1.w);
    const float oo = wave_sum(o0.x*o0.x + o0.y*o0.y + o0.z*o0.z + o0.w*o0.w
                            + o1.x*o1.x + o1.y*o1.y + o1.z*o1.z + o1.w*o1.w);
    const float n_s = fmaxf(sqrtf(ss), 1e-15f);
    const float arg = fminf(fmaxf(sc * n_s, -1.0f + 1e-7f), 1.0f - 1e-7f);
    const float ls  = atanhf(arg) / (sc * n_s);
    const float4 ang = *(const float4*)(grot + 4 * lane);
    float sa0, ca0, sa1, ca1, sa2, ca2, sa3, ca3;
    sincosf(ang.x, &sa0, &ca0); sincosf(ang.y, &sa1, &ca1);
    sincosf(ang.z, &sa2, &ca2); sincosf(ang.w, &sa3, &ca3);
    const float x0 = ls*s0.x, x1 = ls*s0.y, x2v = ls*s0.z, x3 = ls*s0.w;
    const float x4 = ls*s1.x, x5 = ls*s1.y, x6 = ls*s1.z, x7 = ls*s1.w;
    const float ux0 = ca0*x0 - sa0*x1, uy0 = sa0*x0 + ca0*x1;
    const float ux1 = ca1*x2v - sa1*x3, uy1 = sa1*x2v + ca1*x3;
    const float ux2 = ca2*x4 - sa2*x5, uy2 = sa2*x4 + ca2*x5;
    const float ux3 = ca3*x6 - sa3*x7, uy3 = sa3*x6 + ca3*x7;
    const float uo = wave_sum(ux0*o0.x + uy0*o0.y + ux1*o0.z + uy1*o0.w
                            + ux2*o1.x + uy2*o1.y + ux3*o1.z + uy3*o1.w);
    // ||u|| = ls*||s|| (rotation orthogonal); ||es*u|| = es*||u||
    const float n_u = ls * n_s;
    const float tt  = tanhf(sc * n_u);
    const float es  = tt / (sc * n_u);
    const float rn  = tt / sc;               // es * n_u
    const float rr  = rn * rn;
    const float ro  = es * uo;
    const float A1  = 1.0f - 2.0f*c*ro + c*oo;
    const float B1  = 1.0f - c*rr;
    const float den = fmaxf(1.0f - 2.0f*c*ro + c*c*rr*oo, 1e-15f);
    const float inv = 1.0f / den;
    const float qa  = -A1 * es * inv, qb = B1 * inv;
    f16x8 h;
    h[0] = (_Float16)(qa*ux0 + qb*o0.x); h[1] = (_Float16)(qa*uy0 + qb*o0.y);
    h[2] = (_Float16)(qa*ux1 + qb*o0.z); h[3] = (_Float16)(qa*uy1 + qb*o0.w);
    h[4] = (_Float16)(qa*ux2 + qb*o1.x); h[5] = (_Float16)(qa*uy2 + qb*o1.y);
    h[6] = (_Float16)(qa*ux3 + qb*o1.z); h[7] = (_Float16)(qa*uy3 + qb*o1.w);
    *(f16x8*)(A3 + (size_t)b * D + lane * 8) = h;
    if (lane == 0)
        x2[b] = (A1*A1*rr - 2.0f*A1*B1*ro + B1*B1*oo) * inv * inv;
}

// ---- prep: 1536 waves; rel/q interleaved within blocks for tail balance ----
__global__ __launch_bounds__(256) void prep_kernel(
        const float* __restrict__ ent, const float* __restrict__ rel,
        const int* __restrict__ trip, const float* __restrict__ grot,
        _Float16* __restrict__ A3, _Float16* __restrict__ B3,
        float* __restrict__ x2, float* __restrict__ y2) {
    const int t = threadIdx.x, wid = t >> 6, lane = t & 63;
    const int gid = blockIdx.x * 4 + wid;        // 0..1535
    const int g3 = gid / 3;
    if (gid % 3 == 0) prep_rel_row(g3, lane, rel, B3, y2);
    else              prep_q_row(gid - g3 - 1, lane, ent, trip, grot, A3, x2);
}

// ---- score: 64x32 tile / 512-thr block; 8 waves = 2 m-halves x 4 K-quarters
__global__ __launch_bounds__(512) void score_mfma(
        const _Float16* __restrict__ A3, const _Float16* __restrict__ B3,
        const float* __restrict__ x2, const float* __restrict__ y2,
        const float* __restrict__ bias, float* __restrict__ out) {
    const int t = threadIdx.x, wid = t >> 6, lane = t & 63;
    const int wm = wid & 1, kh = wid >> 1;       // kh in 0..3
    const int m0 = blockIdx.y * 64 + wm * 32;
    const int n0 = blockIdx.x * 32;
    const int row = lane & 15, kg = lane >> 4;

    const f16x8* pa0 = (const f16x8*)(A3 + (size_t)(m0 + row) * D) + kg;
    const f16x8* pa1 = (const f16x8*)(A3 + (size_t)(m0 + 16 + row) * D) + kg;
    const f16x8* pb0 = (const f16x8*)(B3 + (size_t)(n0 + row) * D) + kg;
    const f16x8* pb1 = (const f16x8*)(B3 + (size_t)(n0 + 16 + row) * D) + kg;

    f32x4 acc[2][2] = {};
    const int k8beg = kh * 16;                   // K=128 per wave
#pragma unroll
    for (int k8 = k8beg; k8 < k8beg + 16; k8 += 4) {  // 4 iters, unrolled
        const f16x8 a0 = pa0[k8], a1 = pa1[k8];
        const f16x8 b0 = pb0[k8], b1 = pb1[k8];
        acc[0][0] = __builtin_amdgcn_mfma_f32_16x16x32_f16(a0, b0, acc[0][0], 0, 0, 0);
        acc[0][1] = __builtin_amdgcn_mfma_f32_16x16x32_f16(a0, b1, acc[0][1], 0, 0, 0);
        acc[1][0] = __builtin_amdgcn_mfma_f32_16x16x32_f16(a1, b0, acc[1][0], 0, 0, 0);
        acc[1][1] = __builtin_amdgcn_mfma_f32_16x16x32_f16(a1, b1, acc[1][1], 0, 0, 0);
    }

    __shared__ f32x4 lacc[3][2][64][4];          // partials from kh=1..3
    if (kh > 0) {
#pragma unroll
        for (int i = 0; i < 2; ++i)
#pragma unroll
            for (int j = 0; j < 2; ++j)
                lacc[kh - 1][wm][lane][i * 2 + j] = acc[i][j];
    }
    __syncthreads();
    if (kh == 0) {
#pragma unroll
        for (int p = 0; p < 3; ++p)
#pragma unroll
            for (int i = 0; i < 2; ++i)
#pragma unroll
                for (int j = 0; j < 2; ++j)
                    acc[i][j] += lacc[p][wm][lane][i * 2 + j];

        // C/D layout: col = lane&15, row = (lane>>4)*4 + reg
        const float c = 0.01f;
        const int crow = (lane >> 4) * 4;
        const int ccol = lane & 15;
#pragma unroll
        for (int i = 0; i < 2; ++i) {
#pragma unroll
            for (int r = 0; r < 4; ++r) {
                const int m = m0 + i * 16 + crow + r;
                const float X2 = x2[m];
                const float B1 = 1.0f - c * X2;
#pragma unroll
                for (int j = 0; j < 2; ++j) {
                    const int n  = n0 + j * 16 + ccol;
                    const float qd = acc[i][j][r];
                    const float Y2 = y2[n];
                    const float A1  = 1.0f - 2.0f * c * qd + c * Y2;
                    const float den = fmaxf(1.0f - 2.0f * c * qd + c * c * X2 * Y2, 1e-15f);
                    const float num2 = A1 * A1 * X2 - 2.0f * A1 * B1 * qd + B1 * B1 * Y2;
                    out[(size_t)m * NREL + n] = -(num2 / (den * den)) + bias[n];
                }
            }
        }
    }
}

extern "C" void kernel_launch(void* const* d_in, const int* in_sizes, int n_in,
                              void* d_out, int out_size, void* d_ws, size_t ws_size,
                              hipStream_t stream) {
    const float* ent  = (const float*)d_in[0];   // (20000, 512)
    const float* rel  = (const float*)d_in[1];   // (512, 512)
    const int*   trip = (const int*)d_in[2];     // (1024, 3)
    const float* grot = (const float*)d_in[3];   // (256,)
    const float* bias = (const float*)d_in[4];   // (512,)
    float* out = (float*)d_out;                  // (1024, 512)

    _Float16* A3 = (_Float16*)d_ws;              // 1024*512 fp16
    _Float16* B3 = A3 + (size_t)NB * D;          // 512*512 fp16
    float* x2 = (float*)(B3 + (size_t)NREL * D);
    float* y2 = x2 + NB;

    prep_kernel<<<dim3((NREL + NB) / 4), dim3(256), 0, stream>>>(
        ent, rel, trip, grot, A3, B3, x2, y2);
    score_mfma<<<dim3(NREL / 32, NB / 64), dim3(512), 0, stream>>>(
        A3, B3, x2, y2, bias, out);
}